// Round 4
// baseline (929.589 us; speedup 1.0000x reference)
//
#include <hip/hip_runtime.h>
#include <hip/hip_bf16.h>

// ---------------------------------------------------------------------------
// SparseLaneAttention on MI355X (gfx950) — round 4.
// r3 post-mortem: layer_fused ~100us/layer (serial in-kernel gathers + 4x
// redundant weight reads), flash_attn 93us at 10.7% occupancy (latency-bound).
// Fixes: (1) agg_rows kernel materializes per-(type,dest) summed rows ->
// layer GEMM becomes dense K=1920; (2) mega kernel fuses GEMM+GN1+ReLU+
// ctr2-GEMM+GN2+res+ReLU via wave-private LDS transpose; (3) flash KV-split
// x4 chunks + exact combine.
// ---------------------------------------------------------------------------

typedef __bf16 bf16_t;
typedef __attribute__((ext_vector_type(8))) __bf16 bf16x8;
typedef __attribute__((ext_vector_type(4))) __bf16 bf16x4;
typedef __attribute__((ext_vector_type(2))) __bf16 bf16x2;
typedef __attribute__((ext_vector_type(4))) float f32x4;

#define MROWS 16384   // B*N
#define DDIM  128
#define EEDGE 32768
#define NSEQ  1024
#define NBATCH 16
#define CAP   16
#define NTYPE 14
#define NKEY  (NTYPE * MROWS)
#define OVMAX 4096
#define NCHUNK 4      // flash KV split

// ---------------------------------------------------------------------------
// Multi-segment f32 -> bf16 conversion
// ---------------------------------------------------------------------------
struct CvtArgs {
    const float* src[6];
    bf16_t* dst[6];
    int n4[6];
};

__global__ __launch_bounds__(256) void cvt_multi(CvtArgs a, int total4) {
    int i = blockIdx.x * 256 + threadIdx.x;
    if (i >= total4) return;
    int k = 0, base = 0;
    while (i - base >= a.n4[k]) { base += a.n4[k]; ++k; }
    int j = i - base;
    float4 v = reinterpret_cast<const float4*>(a.src[k])[j];
    bf16x4 o = { (bf16_t)v.x, (bf16_t)v.y, (bf16_t)v.z, (bf16_t)v.w };
    reinterpret_cast<bf16x4*>(a.dst[k])[j] = o;
}

// ---------------------------------------------------------------------------
// wcat[layer][15][128][128] bf16; slots 0..5 pre, 6..11 suc, 12 left,
// 13 right, 14 ctr.
// ---------------------------------------------------------------------------
__global__ __launch_bounds__(256) void cvt_wcat(
    const float* __restrict__ W_ctr, const float* __restrict__ W_pre,
    const float* __restrict__ W_suc, const float* __restrict__ W_left,
    const float* __restrict__ W_right, bf16_t* __restrict__ wcat)
{
    int tid = blockIdx.x * 256 + threadIdx.x;
    int idx = tid * 4;
    if (idx >= 4 * 15 * 16384) return;
    const int PER_I = 15 * 16384;
    int i = idx / PER_I, rem = idx % PER_I;
    int slot = rem / 16384, k = rem % 16384;
    const float* src;
    if (slot < 6)       src = W_pre  + ((size_t)(i * 6 + slot) * 16384 + k);
    else if (slot < 12) src = W_suc  + ((size_t)(i * 6 + slot - 6) * 16384 + k);
    else if (slot == 12) src = W_left  + ((size_t)i * 16384 + k);
    else if (slot == 13) src = W_right + ((size_t)i * 16384 + k);
    else                 src = W_ctr   + ((size_t)i * 16384 + k);
    float4 v = *reinterpret_cast<const float4*>(src);
    bf16x4 o = { (bf16_t)v.x, (bf16_t)v.y, (bf16_t)v.z, (bf16_t)v.w };
    *reinterpret_cast<bf16x4*>(wcat + idx) = o;
}

// ---------------------------------------------------------------------------
// Build CSR (once per call; indices are call-invariant).
// ---------------------------------------------------------------------------
__global__ __launch_bounds__(256) void build_csr(
    const int* __restrict__ pre_u, const int* __restrict__ pre_v,
    const int* __restrict__ suc_u, const int* __restrict__ suc_v,
    const int* __restrict__ left_u, const int* __restrict__ left_v,
    const int* __restrict__ right_u, const int* __restrict__ right_v,
    unsigned* __restrict__ cnt, int* __restrict__ csr,
    unsigned* __restrict__ ovcnt, int* __restrict__ ovlist)
{
    int tid = blockIdx.x * 256 + threadIdx.x;
    int t = tid >> 15, e = tid & (EEDGE - 1);
    const int* ua; const int* va;
    if (t < 6)        { ua = pre_u + t * EEDGE;       va = pre_v + t * EEDGE; }
    else if (t < 12)  { ua = suc_u + (t - 6) * EEDGE; va = suc_v + (t - 6) * EEDGE; }
    else if (t == 12) { ua = left_u;  va = left_v; }
    else              { ua = right_u; va = right_v; }
    int u = ua[e], v = va[e];
    int key = t * MROWS + u;
    unsigned slot = atomicAdd(&cnt[key], 1u);
    if (slot < CAP) csr[key * CAP + slot] = v;
    else {
        unsigned o = atomicAdd(ovcnt, 1u);
        if (o < OVMAX) { ovlist[o * 2] = key; ovlist[o * 2 + 1] = v; }
    }
}

// ---------------------------------------------------------------------------
// Aggregate: agg[key][ch] = sum of fin rows per CSR.  One wave per key,
// lane covers 2 channels (4B).  Must write zeros when count==0 (ws poisoned).
// ---------------------------------------------------------------------------
__global__ __launch_bounds__(256) void agg_rows(
    const bf16_t* __restrict__ fin, const unsigned* __restrict__ cnt,
    const int* __restrict__ csr, const unsigned* __restrict__ ovcnt,
    const int* __restrict__ ovlist, bf16_t* __restrict__ agg)
{
    int wid = (blockIdx.x * 256 + threadIdx.x) >> 6;
    int lane = threadIdx.x & 63;
    if (wid >= NKEY) return;
    unsigned craw = cnt[wid];
    int c = (int)(craw < CAP ? craw : CAP);
    float s0 = 0.f, s1 = 0.f;
    const int* lst = csr + (size_t)wid * CAP;
    for (int j = 0; j < c; ++j) {
        bf16x2 x = *reinterpret_cast<const bf16x2*>(fin + (size_t)lst[j] * DDIM + lane * 2);
        s0 += (float)x[0]; s1 += (float)x[1];
    }
    if (craw > CAP) {
        unsigned no = *ovcnt; if (no > OVMAX) no = OVMAX;
        for (unsigned o = 0; o < no; ++o) {
            if (ovlist[o * 2] == wid) {
                bf16x2 x = *reinterpret_cast<const bf16x2*>(fin + (size_t)ovlist[o * 2 + 1] * DDIM + lane * 2);
                s0 += (float)x[0]; s1 += (float)x[1];
            }
        }
    }
    bf16x2 o2 = { (bf16_t)s0, (bf16_t)s1 };
    *reinterpret_cast<bf16x2*>(agg + (size_t)wid * DDIM + lane * 2) = o2;
}

// ---------------------------------------------------------------------------
// QKV projection (unchanged).
// ---------------------------------------------------------------------------
__global__ __launch_bounds__(256) void qkv_gemm(
    const bf16_t* __restrict__ ctrs_bf, const bf16_t* __restrict__ feats_bf,
    const bf16_t* __restrict__ wq, const bf16_t* __restrict__ wk, const bf16_t* __restrict__ wv,
    bf16_t* __restrict__ q_out, bf16_t* __restrict__ k_out, bf16_t* __restrict__ vT_out)
{
    const int which = blockIdx.y;
    const bf16_t* x = (which == 0) ? ctrs_bf : feats_bf;
    const bf16_t* w = (which == 0) ? wq : (which == 1) ? wk : wv;
    const int lane = threadIdx.x & 63, wave = threadIdx.x >> 6;
    const int li = lane & 15, kg = lane >> 4;
    const int row0 = blockIdx.x * 64 + wave * 16;

    bf16x8 a[4];
#pragma unroll
    for (int kk = 0; kk < 4; ++kk)
        a[kk] = *reinterpret_cast<const bf16x8*>(x + (size_t)(row0 + li) * DDIM + kk * 32 + kg * 8);

    f32x4 acc[8];
#pragma unroll
    for (int t = 0; t < 8; ++t) {
        f32x4 c = {0.f, 0.f, 0.f, 0.f};
#pragma unroll
        for (int kk = 0; kk < 4; ++kk) {
            bf16x8 b = *reinterpret_cast<const bf16x8*>(w + (size_t)(t * 16 + li) * DDIM + kk * 32 + kg * 8);
            c = __builtin_amdgcn_mfma_f32_16x16x32_bf16(a[kk], b, c, 0, 0, 0);
        }
        acc[t] = c;
    }

    if (which < 2) {
        bf16_t* out = (which == 0) ? q_out : k_out;
#pragma unroll
        for (int t = 0; t < 8; ++t) {
            int c = t * 16 + li;
#pragma unroll
            for (int r = 0; r < 4; ++r)
                out[(size_t)(row0 + kg * 4 + r) * DDIM + c] = (bf16_t)acc[t][r];
        }
    } else {
        const int bb = row0 >> 10;
        const int jb = (row0 & 1023) + kg * 4;
#pragma unroll
        for (int t = 0; t < 8; ++t) {
            int c = t * 16 + li;
            bf16x4 pk = { (bf16_t)acc[t][0], (bf16_t)acc[t][1], (bf16_t)acc[t][2], (bf16_t)acc[t][3] };
            *reinterpret_cast<bf16x4*>(vT_out + ((size_t)bb * 128 + c) * NSEQ + jb) = pk;
        }
    }
}

// ---------------------------------------------------------------------------
// Flash attention, KV-split: blockIdx.z = chunk (256 keys each).  Writes
// UNNORMALIZED partial O plus per-row (m,l) for the combine pass.
// ---------------------------------------------------------------------------
__global__ __launch_bounds__(256) void flash_attn(
    const bf16_t* __restrict__ q, const bf16_t* __restrict__ k,
    const bf16_t* __restrict__ vT,
    float* __restrict__ pO, float* __restrict__ pm, float* __restrict__ pl)
{
    const int lane = threadIdx.x & 63, wave = threadIdx.x >> 6;
    const int li = lane & 15, kg = lane >> 4;
    const int b = blockIdx.y;
    const int chunk = blockIdx.z;
    const int i0 = blockIdx.x * 64 + wave * 16;

    __shared__ bf16_t p_lds[4][16][48];

    bf16x8 qf[4];
#pragma unroll
    for (int kk = 0; kk < 4; ++kk)
        qf[kk] = *reinterpret_cast<const bf16x8*>(q + ((size_t)b * NSEQ + i0 + li) * DDIM + kk * 32 + kg * 8);

    float m_run = -1e30f, l_run = 0.f;
    f32x4 o[8];
#pragma unroll
    for (int t = 0; t < 8; ++t) o[t] = f32x4{0.f, 0.f, 0.f, 0.f};

    const float nf = 0.08838834764831845f;
    const int jlo = chunk * (NSEQ / NCHUNK), jhi = jlo + NSEQ / NCHUNK;

    for (int j0 = jlo; j0 < jhi; j0 += 32) {
        f32x4 s[2];
#pragma unroll
        for (int sub = 0; sub < 2; ++sub) {
            f32x4 c = {0.f, 0.f, 0.f, 0.f};
#pragma unroll
            for (int kk = 0; kk < 4; ++kk) {
                bf16x8 a = *reinterpret_cast<const bf16x8*>(
                    k + ((size_t)b * NSEQ + j0 + sub * 16 + li) * DDIM + kk * 32 + kg * 8);
                c = __builtin_amdgcn_mfma_f32_16x16x32_bf16(a, qf[kk], c, 0, 0, 0);
            }
            s[sub] = c;
        }
        float smax = -1e30f;
#pragma unroll
        for (int sub = 0; sub < 2; ++sub)
#pragma unroll
            for (int r = 0; r < 4; ++r) { s[sub][r] *= nf; smax = fmaxf(smax, s[sub][r]); }
        smax = fmaxf(smax, __shfl_xor(smax, 16));
        smax = fmaxf(smax, __shfl_xor(smax, 32));
        float m_new = fmaxf(m_run, smax);
        float alpha = __expf(m_run - m_new);
        float psum = 0.f;
#pragma unroll
        for (int sub = 0; sub < 2; ++sub) {
            bf16x4 pk;
#pragma unroll
            for (int r = 0; r < 4; ++r) {
                float p = __expf(s[sub][r] - m_new);
                psum += p;
                pk[r] = (bf16_t)p;
            }
            *reinterpret_cast<bf16x4*>(&p_lds[wave][li][sub * 16 + kg * 4]) = pk;
        }
        psum += __shfl_xor(psum, 16);
        psum += __shfl_xor(psum, 32);
        l_run = l_run * alpha + psum;
        m_run = m_new;

        float al[4];
#pragma unroll
        for (int r = 0; r < 4; ++r) al[r] = __shfl(alpha, kg * 4 + r);

        asm volatile("s_waitcnt lgkmcnt(0)" ::: "memory");
        __builtin_amdgcn_sched_barrier(0);

        bf16x8 pa = *reinterpret_cast<const bf16x8*>(&p_lds[wave][li][kg * 8]);

#pragma unroll
        for (int t = 0; t < 8; ++t)
#pragma unroll
            for (int r = 0; r < 4; ++r) o[t][r] *= al[r];

#pragma unroll
        for (int t = 0; t < 8; ++t) {
            bf16x8 vb = *reinterpret_cast<const bf16x8*>(
                vT + ((size_t)b * 128 + t * 16 + li) * NSEQ + j0 + kg * 8);
            o[t] = __builtin_amdgcn_mfma_f32_16x16x32_bf16(pa, vb, o[t], 0, 0, 0);
        }
    }

    // store unnormalized partials
#pragma unroll
    for (int t = 0; t < 8; ++t) {
        int c = t * 16 + li;
#pragma unroll
        for (int r = 0; r < 4; ++r) {
            size_t m = (size_t)b * NSEQ + i0 + kg * 4 + r;
            pO[((size_t)chunk * MROWS + m) * DDIM + c] = o[t][r];
        }
    }
    float m_r[4], l_r[4];
#pragma unroll
    for (int r = 0; r < 4; ++r) { m_r[r] = __shfl(m_run, kg * 4 + r); l_r[r] = __shfl(l_run, kg * 4 + r); }
    if (li == 0) {
#pragma unroll
        for (int r = 0; r < 4; ++r) {
            size_t m = (size_t)b * NSEQ + i0 + kg * 4 + r;
            pm[(size_t)chunk * MROWS + m] = m_r[r];
            pl[(size_t)chunk * MROWS + m] = l_r[r];
        }
    }
}

// ---------------------------------------------------------------------------
// Combine chunk partials (exact): att = sum_c e^{m_c-M} O_c / sum_c e^{m_c-M} l_c.
// feat = feats + att -> bf16 feat + f32 res.
// ---------------------------------------------------------------------------
__global__ __launch_bounds__(256) void attn_combine(
    const float* __restrict__ pO, const float* __restrict__ pm, const float* __restrict__ pl,
    const float* __restrict__ feats, bf16_t* __restrict__ feat_bf, float* __restrict__ res)
{
    int idx = blockIdx.x * 256 + threadIdx.x;
    int row = idx >> 7;
    float mx = -1e30f;
#pragma unroll
    for (int c = 0; c < NCHUNK; ++c) mx = fmaxf(mx, pm[(size_t)c * MROWS + row]);
    float num = 0.f, den = 0.f;
#pragma unroll
    for (int c = 0; c < NCHUNK; ++c) {
        float wgt = __expf(pm[(size_t)c * MROWS + row] - mx);
        den += wgt * pl[(size_t)c * MROWS + row];
        num += wgt * pO[((size_t)c * MROWS + row) * DDIM + (idx & 127)];
    }
    float f = feats[idx] + num / den;
    feat_bf[idx] = (bf16_t)f;
    res[idx] = f;
}

// ---------------------------------------------------------------------------
// Mega layer kernel.  Block = 64 rows (4 waves x 16).  K-loop over 15 blocks:
// A = agg slab (kb<14) or fin (kb==14), W = wcat slot kb.  Epilogue fuses
// GN1+ReLU -> LDS transpose -> ctr2 GEMM -> GN2 + residual + ReLU.
// ---------------------------------------------------------------------------
__global__ __launch_bounds__(256) void layer_mega(
    const bf16_t* __restrict__ fin, const bf16_t* __restrict__ agg,
    const bf16_t* __restrict__ wcat_l, const bf16_t* __restrict__ wctr2_l,
    const float* __restrict__ g1, const float* __restrict__ b1,
    const float* __restrict__ g2, const float* __restrict__ b2,
    float* __restrict__ res, bf16_t* __restrict__ fout, float* __restrict__ out_f32)
{
    __shared__ bf16_t y_lds[4][16][130];   // stride 130: spreads banks on b128 reads
    const int lane = threadIdx.x & 63, w = threadIdx.x >> 6;
    const int li = lane & 15, kg = lane >> 4;
    const int rowA = blockIdx.x * 64 + w * 16;

    f32x4 acc[8];
#pragma unroll
    for (int t8 = 0; t8 < 8; ++t8) acc[t8] = f32x4{0.f, 0.f, 0.f, 0.f};

    for (int kb = 0; kb < 15; ++kb) {
        const bf16_t* abase = (kb == 14) ? fin : agg + (size_t)kb * MROWS * DDIM;
        bf16x8 af[4];
#pragma unroll
        for (int kk = 0; kk < 4; ++kk)
            af[kk] = *reinterpret_cast<const bf16x8*>(abase + (size_t)(rowA + li) * DDIM + kk * 32 + kg * 8);
        const bf16_t* wt = wcat_l + (size_t)kb * 16384;
#pragma unroll
        for (int t8 = 0; t8 < 8; ++t8)
#pragma unroll
            for (int kk = 0; kk < 4; ++kk) {
                bf16x8 bfrag = *reinterpret_cast<const bf16x8*>(wt + (size_t)(t8 * 16 + li) * DDIM + kk * 32 + kg * 8);
                acc[t8] = __builtin_amdgcn_mfma_f32_16x16x32_bf16(af[kk], bfrag, acc[t8], 0, 0, 0);
            }
    }

    // ---- GN1 stats (row = kg*4+r, channels = t8 in-reg x li cross-lane) ----
    float mu1[4], rs1[4];
#pragma unroll
    for (int r = 0; r < 4; ++r) {
        float s = 0.f, sq = 0.f;
#pragma unroll
        for (int t8 = 0; t8 < 8; ++t8) { float v = acc[t8][r]; s += v; sq += v * v; }
#pragma unroll
        for (int msk = 1; msk < 16; msk <<= 1) { s += __shfl_xor(s, msk); sq += __shfl_xor(sq, msk); }
        float mu = s * (1.f / 128.f);
        float var = sq * (1.f / 128.f) - mu * mu;
        mu1[r] = mu;
        rs1[r] = rsqrtf(var + 1e-5f);
    }

    // ---- y = relu(gn1) -> wave-private LDS (C layout -> A layout) ----
#pragma unroll
    for (int t8 = 0; t8 < 8; ++t8) {
        int c = t8 * 16 + li;
        float gg = g1[c], bb = b1[c];
#pragma unroll
        for (int r = 0; r < 4; ++r) {
            float y = fmaxf((acc[t8][r] - mu1[r]) * rs1[r] * gg + bb, 0.f);
            y_lds[w][kg * 4 + r][c] = (bf16_t)y;
        }
    }
    __syncthreads();

    bf16x8 af2[4];
#pragma unroll
    for (int kk = 0; kk < 4; ++kk)
        af2[kk] = *reinterpret_cast<const bf16x8*>(&y_lds[w][li][kk * 32 + kg * 8]);

    f32x4 acc2[8];
#pragma unroll
    for (int t8 = 0; t8 < 8; ++t8) acc2[t8] = f32x4{0.f, 0.f, 0.f, 0.f};
#pragma unroll
    for (int t8 = 0; t8 < 8; ++t8)
#pragma unroll
        for (int kk = 0; kk < 4; ++kk) {
            bf16x8 bfrag = *reinterpret_cast<const bf16x8*>(wctr2_l + (size_t)(t8 * 16 + li) * DDIM + kk * 32 + kg * 8);
            acc2[t8] = __builtin_amdgcn_mfma_f32_16x16x32_bf16(af2[kk], bfrag, acc2[t8], 0, 0, 0);
        }

    // ---- GN2 stats ----
    float mu2[4], rs2[4];
#pragma unroll
    for (int r = 0; r < 4; ++r) {
        float s = 0.f, sq = 0.f;
#pragma unroll
        for (int t8 = 0; t8 < 8; ++t8) { float v = acc2[t8][r]; s += v; sq += v * v; }
#pragma unroll
        for (int msk = 1; msk < 16; msk <<= 1) { s += __shfl_xor(s, msk); sq += __shfl_xor(sq, msk); }
        float mu = s * (1.f / 128.f);
        float var = sq * (1.f / 128.f) - mu * mu;
        mu2[r] = mu;
        rs2[r] = rsqrtf(var + 1e-5f);
    }

    // ---- epilogue: f = relu(gn2 + res); update res, fout, optional d_out ----
#pragma unroll
    for (int t8 = 0; t8 < 8; ++t8) {
        int c = t8 * 16 + li;
        float gg = g2[c], bb = b2[c];
#pragma unroll
        for (int r = 0; r < 4; ++r) {
            size_t idx = (size_t)(rowA + kg * 4 + r) * DDIM + c;
            float y = (acc2[t8][r] - mu2[r]) * rs2[r] * gg + bb;
            float f = fmaxf(y + res[idx], 0.f);
            res[idx] = f;
            fout[idx] = (bf16_t)f;
            if (out_f32) out_f32[idx] = f;
        }
    }
}

// ---------------------------------------------------------------------------
// Host launch
// ---------------------------------------------------------------------------
extern "C" void kernel_launch(void* const* d_in, const int* in_sizes, int n_in,
                              void* d_out, int out_size, void* d_ws, size_t ws_size,
                              hipStream_t stream) {
    const float* ctrs   = (const float*)d_in[0];
    const float* feats  = (const float*)d_in[1];
    const float* Wq     = (const float*)d_in[2];
    const float* Wk     = (const float*)d_in[3];
    const float* Wv     = (const float*)d_in[4];
    const float* W_ctr  = (const float*)d_in[5];
    const float* W_pre  = (const float*)d_in[6];
    const float* W_suc  = (const float*)d_in[7];
    const float* W_left = (const float*)d_in[8];
    const float* W_right= (const float*)d_in[9];
    const float* W_ctr2 = (const float*)d_in[10];
    const float* gn_g   = (const float*)d_in[11];
    const float* gn_b   = (const float*)d_in[12];
    const float* gn2_g  = (const float*)d_in[13];
    const float* gn2_b  = (const float*)d_in[14];
    const int* pre_u    = (const int*)d_in[15];
    const int* pre_v    = (const int*)d_in[16];
    const int* suc_u    = (const int*)d_in[17];
    const int* suc_v    = (const int*)d_in[18];
    const int* left_u   = (const int*)d_in[19];
    const int* left_v   = (const int*)d_in[20];
    const int* right_u  = (const int*)d_in[21];
    const int* right_v  = (const int*)d_in[22];
    (void)in_sizes; (void)n_in; (void)out_size; (void)ws_size;

    size_t off = 0;
    auto alloc = [&](size_t bytes) -> void* {
        void* p = (char*)d_ws + off;
        off += (bytes + 255) & ~(size_t)255;
        return p;
    };
    // persistent region
    bf16_t* wq_b    = (bf16_t*)alloc(16384 * 2);
    bf16_t* wk_b    = (bf16_t*)alloc(16384 * 2);
    bf16_t* wv_b    = (bf16_t*)alloc(16384 * 2);
    bf16_t* wctr2_b = (bf16_t*)alloc(65536 * 2);
    bf16_t* wcat    = (bf16_t*)alloc((size_t)4 * 15 * 16384 * 2);
    bf16_t* featA   = (bf16_t*)alloc((size_t)MROWS * DDIM * 2);
    bf16_t* featB   = (bf16_t*)alloc((size_t)MROWS * DDIM * 2);
    float*  res_f   = (float*)alloc((size_t)MROWS * DDIM * 4);
    unsigned* cnt   = (unsigned*)alloc((size_t)NKEY * 4);
    unsigned* ovcnt = (unsigned*)alloc(256);
    int*    csr     = (int*)alloc((size_t)NKEY * CAP * 4);
    int*    ovlist  = (int*)alloc((size_t)OVMAX * 2 * 4);

    // union region: attention-phase buffers vs per-layer agg slabs
    size_t uoff = off;
    auto ualloc = [&](size_t bytes) -> void* {
        void* p = (char*)d_ws + uoff;
        uoff += (bytes + 255) & ~(size_t)255;
        return p;
    };
    bf16_t* ctrs_b  = (bf16_t*)ualloc((size_t)MROWS * DDIM * 2);
    bf16_t* feats_b = (bf16_t*)ualloc((size_t)MROWS * DDIM * 2);
    bf16_t* q_b     = (bf16_t*)ualloc((size_t)MROWS * DDIM * 2);
    bf16_t* k_b     = (bf16_t*)ualloc((size_t)MROWS * DDIM * 2);
    bf16_t* vT_b    = (bf16_t*)ualloc((size_t)MROWS * DDIM * 2);
    float*  pm      = (float*)ualloc((size_t)NCHUNK * MROWS * 4);
    float*  pl      = (float*)ualloc((size_t)NCHUNK * MROWS * 4);
    float*  pO      = (float*)ualloc((size_t)NCHUNK * MROWS * DDIM * 4);
    bf16_t* agg     = (bf16_t*)((char*)d_ws + off);   // overlays the attn-phase buffers

    // --- preprocessing ---
    hipMemsetAsync(cnt, 0, (size_t)NKEY * 4 + 256, stream);  // cnt + ovcnt

    CvtArgs ca;
    ca.src[0] = ctrs;   ca.dst[0] = ctrs_b;  ca.n4[0] = MROWS * DDIM / 4;
    ca.src[1] = feats;  ca.dst[1] = feats_b; ca.n4[1] = MROWS * DDIM / 4;
    ca.src[2] = Wq;     ca.dst[2] = wq_b;    ca.n4[2] = 16384 / 4;
    ca.src[3] = Wk;     ca.dst[3] = wk_b;    ca.n4[3] = 16384 / 4;
    ca.src[4] = Wv;     ca.dst[4] = wv_b;    ca.n4[4] = 16384 / 4;
    ca.src[5] = W_ctr2; ca.dst[5] = wctr2_b; ca.n4[5] = 65536 / 4;
    int total4 = (2 * MROWS * DDIM + 3 * 16384 + 65536) / 4;
    cvt_multi<<<dim3((total4 + 255) / 256), dim3(256), 0, stream>>>(ca, total4);

    cvt_wcat<<<dim3((4 * 15 * 16384 / 4 + 255) / 256), dim3(256), 0, stream>>>(
        W_ctr, W_pre, W_suc, W_left, W_right, wcat);

    build_csr<<<dim3(NTYPE * EEDGE / 256), dim3(256), 0, stream>>>(
        pre_u, pre_v, suc_u, suc_v, left_u, left_v, right_u, right_v,
        cnt, csr, ovcnt, ovlist);

    // --- attention ---
    qkv_gemm<<<dim3(MROWS / 64, 3), dim3(256), 0, stream>>>(
        ctrs_b, feats_b, wq_b, wk_b, wv_b, q_b, k_b, vT_b);

    flash_attn<<<dim3(NSEQ / 64, NBATCH, NCHUNK), dim3(256), 0, stream>>>(
        q_b, k_b, vT_b, pO, pm, pl);

    attn_combine<<<dim3(MROWS * DDIM / 256), dim3(256), 0, stream>>>(
        pO, pm, pl, feats, featA, res_f);

    // --- fusion layers ---
    bf16_t* cur = featA;
    bf16_t* nxt = featB;
    for (int i = 0; i < 4; ++i) {
        agg_rows<<<dim3(NKEY / 4), dim3(256), 0, stream>>>(
            cur, cnt, csr, ovcnt, ovlist, agg);
        layer_mega<<<dim3(MROWS / 64), dim3(256), 0, stream>>>(
            cur, agg, wcat + (size_t)i * 15 * 16384, wctr2_b + (size_t)i * 16384,
            gn_g + i * 128, gn_b + i * 128, gn2_g + i * 128, gn2_b + i * 128,
            res_f, nxt, (i == 3) ? (float*)d_out : nullptr);
        bf16_t* tmp = cur; cur = nxt; nxt = tmp;
    }
}

// Round 5
// 834.574 us; speedup vs baseline: 1.1138x; 1.1138x over previous
//
#include <hip/hip_runtime.h>
#include <hip/hip_bf16.h>

// ---------------------------------------------------------------------------
// SparseLaneAttention on MI355X (gfx950) — round 5.
// r4 post-mortem: split agg+mega regressed (929us): 1 block/CU latency-bound
// mega + 59MB/layer agg round-trip. feat (4MB bf16) is L2-resident, so fused
// in-GEMM gathers are cheap. Revert to fused layer kernel, but cut the serial
// chain: 8 waves x (<=2 types each), LDS f32 atomic reduce into one [16][132]
// tile, GN1+ReLU fused. Flash KV-split x4 + exact combine kept from r4.
// ---------------------------------------------------------------------------

typedef __bf16 bf16_t;
typedef __attribute__((ext_vector_type(8))) __bf16 bf16x8;
typedef __attribute__((ext_vector_type(4))) __bf16 bf16x4;
typedef __attribute__((ext_vector_type(4))) float f32x4;

#define MROWS 16384   // B*N
#define DDIM  128
#define EEDGE 32768
#define NSEQ  1024
#define NBATCH 16
#define CAP   16
#define NTYPE 14
#define NKEY  (NTYPE * MROWS)
#define OVMAX 4096
#define NCHUNK 4      // flash KV split

// ---------------------------------------------------------------------------
// Multi-segment f32 -> bf16 conversion
// ---------------------------------------------------------------------------
struct CvtArgs {
    const float* src[6];
    bf16_t* dst[6];
    int n4[6];
};

__global__ __launch_bounds__(256) void cvt_multi(CvtArgs a, int total4) {
    int i = blockIdx.x * 256 + threadIdx.x;
    if (i >= total4) return;
    int k = 0, base = 0;
    while (i - base >= a.n4[k]) { base += a.n4[k]; ++k; }
    int j = i - base;
    float4 v = reinterpret_cast<const float4*>(a.src[k])[j];
    bf16x4 o = { (bf16_t)v.x, (bf16_t)v.y, (bf16_t)v.z, (bf16_t)v.w };
    reinterpret_cast<bf16x4*>(a.dst[k])[j] = o;
}

// ---------------------------------------------------------------------------
// wcat[layer][15][128][128] bf16; slots 0..5 pre, 6..11 suc, 12 left,
// 13 right, 14 ctr.
// ---------------------------------------------------------------------------
__global__ __launch_bounds__(256) void cvt_wcat(
    const float* __restrict__ W_ctr, const float* __restrict__ W_pre,
    const float* __restrict__ W_suc, const float* __restrict__ W_left,
    const float* __restrict__ W_right, bf16_t* __restrict__ wcat)
{
    int tid = blockIdx.x * 256 + threadIdx.x;
    int idx = tid * 4;
    if (idx >= 4 * 15 * 16384) return;
    const int PER_I = 15 * 16384;
    int i = idx / PER_I, rem = idx % PER_I;
    int slot = rem / 16384, k = rem % 16384;
    const float* src;
    if (slot < 6)       src = W_pre  + ((size_t)(i * 6 + slot) * 16384 + k);
    else if (slot < 12) src = W_suc  + ((size_t)(i * 6 + slot - 6) * 16384 + k);
    else if (slot == 12) src = W_left  + ((size_t)i * 16384 + k);
    else if (slot == 13) src = W_right + ((size_t)i * 16384 + k);
    else                 src = W_ctr   + ((size_t)i * 16384 + k);
    float4 v = *reinterpret_cast<const float4*>(src);
    bf16x4 o = { (bf16_t)v.x, (bf16_t)v.y, (bf16_t)v.z, (bf16_t)v.w };
    *reinterpret_cast<bf16x4*>(wcat + idx) = o;
}

// ---------------------------------------------------------------------------
// Build CSR (once per call; indices are call-invariant).
// ---------------------------------------------------------------------------
__global__ __launch_bounds__(256) void build_csr(
    const int* __restrict__ pre_u, const int* __restrict__ pre_v,
    const int* __restrict__ suc_u, const int* __restrict__ suc_v,
    const int* __restrict__ left_u, const int* __restrict__ left_v,
    const int* __restrict__ right_u, const int* __restrict__ right_v,
    unsigned* __restrict__ cnt, int* __restrict__ csr,
    unsigned* __restrict__ ovcnt, int* __restrict__ ovlist)
{
    int tid = blockIdx.x * 256 + threadIdx.x;
    int t = tid >> 15, e = tid & (EEDGE - 1);
    const int* ua; const int* va;
    if (t < 6)        { ua = pre_u + t * EEDGE;       va = pre_v + t * EEDGE; }
    else if (t < 12)  { ua = suc_u + (t - 6) * EEDGE; va = suc_v + (t - 6) * EEDGE; }
    else if (t == 12) { ua = left_u;  va = left_v; }
    else              { ua = right_u; va = right_v; }
    int u = ua[e], v = va[e];
    int key = t * MROWS + u;
    unsigned slot = atomicAdd(&cnt[key], 1u);
    if (slot < CAP) csr[key * CAP + slot] = v;
    else {
        unsigned o = atomicAdd(ovcnt, 1u);
        if (o < OVMAX) { ovlist[o * 2] = key; ovlist[o * 2 + 1] = v; }
    }
}

// ---------------------------------------------------------------------------
// QKV projection.
// ---------------------------------------------------------------------------
__global__ __launch_bounds__(256) void qkv_gemm(
    const bf16_t* __restrict__ ctrs_bf, const bf16_t* __restrict__ feats_bf,
    const bf16_t* __restrict__ wq, const bf16_t* __restrict__ wk, const bf16_t* __restrict__ wv,
    bf16_t* __restrict__ q_out, bf16_t* __restrict__ k_out, bf16_t* __restrict__ vT_out)
{
    const int which = blockIdx.y;
    const bf16_t* x = (which == 0) ? ctrs_bf : feats_bf;
    const bf16_t* w = (which == 0) ? wq : (which == 1) ? wk : wv;
    const int lane = threadIdx.x & 63, wave = threadIdx.x >> 6;
    const int li = lane & 15, kg = lane >> 4;
    const int row0 = blockIdx.x * 64 + wave * 16;

    bf16x8 a[4];
#pragma unroll
    for (int kk = 0; kk < 4; ++kk)
        a[kk] = *reinterpret_cast<const bf16x8*>(x + (size_t)(row0 + li) * DDIM + kk * 32 + kg * 8);

    f32x4 acc[8];
#pragma unroll
    for (int t = 0; t < 8; ++t) {
        f32x4 c = {0.f, 0.f, 0.f, 0.f};
#pragma unroll
        for (int kk = 0; kk < 4; ++kk) {
            bf16x8 b = *reinterpret_cast<const bf16x8*>(w + (size_t)(t * 16 + li) * DDIM + kk * 32 + kg * 8);
            c = __builtin_amdgcn_mfma_f32_16x16x32_bf16(a[kk], b, c, 0, 0, 0);
        }
        acc[t] = c;
    }

    if (which < 2) {
        bf16_t* out = (which == 0) ? q_out : k_out;
#pragma unroll
        for (int t = 0; t < 8; ++t) {
            int c = t * 16 + li;
#pragma unroll
            for (int r = 0; r < 4; ++r)
                out[(size_t)(row0 + kg * 4 + r) * DDIM + c] = (bf16_t)acc[t][r];
        }
    } else {
        const int bb = row0 >> 10;
        const int jb = (row0 & 1023) + kg * 4;
#pragma unroll
        for (int t = 0; t < 8; ++t) {
            int c = t * 16 + li;
            bf16x4 pk = { (bf16_t)acc[t][0], (bf16_t)acc[t][1], (bf16_t)acc[t][2], (bf16_t)acc[t][3] };
            *reinterpret_cast<bf16x4*>(vT_out + ((size_t)bb * 128 + c) * NSEQ + jb) = pk;
        }
    }
}

// ---------------------------------------------------------------------------
// Flash attention, KV-split: blockIdx.z = chunk (256 keys each).  Writes
// UNNORMALIZED partial O plus per-row (m,l) for the combine pass.
// ---------------------------------------------------------------------------
__global__ __launch_bounds__(256) void flash_attn(
    const bf16_t* __restrict__ q, const bf16_t* __restrict__ k,
    const bf16_t* __restrict__ vT,
    float* __restrict__ pO, float* __restrict__ pm, float* __restrict__ pl)
{
    const int lane = threadIdx.x & 63, wave = threadIdx.x >> 6;
    const int li = lane & 15, kg = lane >> 4;
    const int b = blockIdx.y;
    const int chunk = blockIdx.z;
    const int i0 = blockIdx.x * 64 + wave * 16;

    __shared__ bf16_t p_lds[4][16][48];

    bf16x8 qf[4];
#pragma unroll
    for (int kk = 0; kk < 4; ++kk)
        qf[kk] = *reinterpret_cast<const bf16x8*>(q + ((size_t)b * NSEQ + i0 + li) * DDIM + kk * 32 + kg * 8);

    float m_run = -1e30f, l_run = 0.f;
    f32x4 o[8];
#pragma unroll
    for (int t = 0; t < 8; ++t) o[t] = f32x4{0.f, 0.f, 0.f, 0.f};

    const float nf = 0.08838834764831845f;
    const int jlo = chunk * (NSEQ / NCHUNK), jhi = jlo + NSEQ / NCHUNK;

    for (int j0 = jlo; j0 < jhi; j0 += 32) {
        f32x4 s[2];
#pragma unroll
        for (int sub = 0; sub < 2; ++sub) {
            f32x4 c = {0.f, 0.f, 0.f, 0.f};
#pragma unroll
            for (int kk = 0; kk < 4; ++kk) {
                bf16x8 a = *reinterpret_cast<const bf16x8*>(
                    k + ((size_t)b * NSEQ + j0 + sub * 16 + li) * DDIM + kk * 32 + kg * 8);
                c = __builtin_amdgcn_mfma_f32_16x16x32_bf16(a, qf[kk], c, 0, 0, 0);
            }
            s[sub] = c;
        }
        float smax = -1e30f;
#pragma unroll
        for (int sub = 0; sub < 2; ++sub)
#pragma unroll
            for (int r = 0; r < 4; ++r) { s[sub][r] *= nf; smax = fmaxf(smax, s[sub][r]); }
        smax = fmaxf(smax, __shfl_xor(smax, 16));
        smax = fmaxf(smax, __shfl_xor(smax, 32));
        float m_new = fmaxf(m_run, smax);
        float alpha = __expf(m_run - m_new);
        float psum = 0.f;
#pragma unroll
        for (int sub = 0; sub < 2; ++sub) {
            bf16x4 pk;
#pragma unroll
            for (int r = 0; r < 4; ++r) {
                float p = __expf(s[sub][r] - m_new);
                psum += p;
                pk[r] = (bf16_t)p;
            }
            *reinterpret_cast<bf16x4*>(&p_lds[wave][li][sub * 16 + kg * 4]) = pk;
        }
        psum += __shfl_xor(psum, 16);
        psum += __shfl_xor(psum, 32);
        l_run = l_run * alpha + psum;
        m_run = m_new;

        float al[4];
#pragma unroll
        for (int r = 0; r < 4; ++r) al[r] = __shfl(alpha, kg * 4 + r);

        asm volatile("s_waitcnt lgkmcnt(0)" ::: "memory");
        __builtin_amdgcn_sched_barrier(0);

        bf16x8 pa = *reinterpret_cast<const bf16x8*>(&p_lds[wave][li][kg * 8]);

#pragma unroll
        for (int t = 0; t < 8; ++t)
#pragma unroll
            for (int r = 0; r < 4; ++r) o[t][r] *= al[r];

#pragma unroll
        for (int t = 0; t < 8; ++t) {
            bf16x8 vb = *reinterpret_cast<const bf16x8*>(
                vT + ((size_t)b * 128 + t * 16 + li) * NSEQ + j0 + kg * 8);
            o[t] = __builtin_amdgcn_mfma_f32_16x16x32_bf16(pa, vb, o[t], 0, 0, 0);
        }
    }

#pragma unroll
    for (int t = 0; t < 8; ++t) {
        int c = t * 16 + li;
#pragma unroll
        for (int r = 0; r < 4; ++r) {
            size_t m = (size_t)b * NSEQ + i0 + kg * 4 + r;
            pO[((size_t)chunk * MROWS + m) * DDIM + c] = o[t][r];
        }
    }
    float m_r[4], l_r[4];
#pragma unroll
    for (int r = 0; r < 4; ++r) { m_r[r] = __shfl(m_run, kg * 4 + r); l_r[r] = __shfl(l_run, kg * 4 + r); }
    if (li == 0) {
#pragma unroll
        for (int r = 0; r < 4; ++r) {
            size_t m = (size_t)b * NSEQ + i0 + kg * 4 + r;
            pm[(size_t)chunk * MROWS + m] = m_r[r];
            pl[(size_t)chunk * MROWS + m] = l_r[r];
        }
    }
}

// ---------------------------------------------------------------------------
// Combine chunk partials (exact) -> feat = feats + att.
// ---------------------------------------------------------------------------
__global__ __launch_bounds__(256) void attn_combine(
    const float* __restrict__ pO, const float* __restrict__ pm, const float* __restrict__ pl,
    const float* __restrict__ feats, bf16_t* __restrict__ feat_bf, float* __restrict__ res)
{
    int idx = blockIdx.x * 256 + threadIdx.x;
    int row = idx >> 7;
    float mx = -1e30f;
#pragma unroll
    for (int c = 0; c < NCHUNK; ++c) mx = fmaxf(mx, pm[(size_t)c * MROWS + row]);
    float num = 0.f, den = 0.f;
#pragma unroll
    for (int c = 0; c < NCHUNK; ++c) {
        float wgt = __expf(pm[(size_t)c * MROWS + row] - mx);
        den += wgt * pl[(size_t)c * MROWS + row];
        num += wgt * pO[((size_t)c * MROWS + row) * DDIM + (idx & 127)];
    }
    float f = feats[idx] + num / den;
    feat_bf[idx] = (bf16_t)f;
    res[idx] = f;
}

// ---------------------------------------------------------------------------
// Fused layer kernel v2.  Block = 16 rows, 512 threads (8 waves).
// Wave w handles types {w, w+8} (wave 7: type 7 only); type 14 = dense ctr.
// Each wave: gather-sum CSR rows (2-way ILP) -> bf16 A-frag -> 32 MFMA,
// accumulating both its types into acc; then f32 atomicAdd into one LDS
// [16][132] tile (stride 132 => free 2-way bank aliasing).  GN1+ReLU fused:
// wave w normalizes rows w and w+8.  No global atomics.
// ---------------------------------------------------------------------------
__global__ __launch_bounds__(512, 4) void layer_fused2(
    const bf16_t* __restrict__ fin, const bf16_t* __restrict__ wcat_l,
    const unsigned* __restrict__ cnt, const int* __restrict__ csr,
    const unsigned* __restrict__ ovcnt, const int* __restrict__ ovlist,
    const float* __restrict__ g, const float* __restrict__ b,
    bf16_t* __restrict__ fout)
{
    __shared__ float tile[16 * 132];
    const int tid = threadIdx.x;
    const int lane = tid & 63, w = tid >> 6;      // w in 0..7
    const int li = lane & 15, kg = lane >> 4;
    const int row0 = blockIdx.x * 16;
    const int row = row0 + li;

    for (int i = tid; i < 16 * 132; i += 512) tile[i] = 0.f;
    __syncthreads();

    f32x4 acc[8];
#pragma unroll
    for (int t8 = 0; t8 < 8; ++t8) acc[t8] = f32x4{0.f, 0.f, 0.f, 0.f};

    for (int t = w; t < 15; t += 8) {
        bf16x8 af[4];
        if (t == 14) {
#pragma unroll
            for (int kk = 0; kk < 4; ++kk)
                af[kk] = *reinterpret_cast<const bf16x8*>(fin + (size_t)row * DDIM + kk * 32 + kg * 8);
        } else {
            const int key = t * MROWS + row;
            const unsigned craw = cnt[key];
            const int c = (int)(craw < CAP ? craw : CAP);
            float s[4][8];
#pragma unroll
            for (int kk = 0; kk < 4; ++kk)
#pragma unroll
                for (int z = 0; z < 8; ++z) s[kk][z] = 0.f;
            const int* lst = csr + (size_t)key * CAP;
            int j = 0;
            for (; j + 2 <= c; j += 2) {
                const bf16_t* p0 = fin + (size_t)lst[j] * DDIM + kg * 8;
                const bf16_t* p1 = fin + (size_t)lst[j + 1] * DDIM + kg * 8;
                bf16x8 x0[4], x1[4];
#pragma unroll
                for (int kk = 0; kk < 4; ++kk) {
                    x0[kk] = *reinterpret_cast<const bf16x8*>(p0 + kk * 32);
                    x1[kk] = *reinterpret_cast<const bf16x8*>(p1 + kk * 32);
                }
#pragma unroll
                for (int kk = 0; kk < 4; ++kk)
#pragma unroll
                    for (int z = 0; z < 8; ++z) s[kk][z] += (float)x0[kk][z] + (float)x1[kk][z];
            }
            if (j < c) {
                const bf16_t* p0 = fin + (size_t)lst[j] * DDIM + kg * 8;
#pragma unroll
                for (int kk = 0; kk < 4; ++kk) {
                    bf16x8 x = *reinterpret_cast<const bf16x8*>(p0 + kk * 32);
#pragma unroll
                    for (int z = 0; z < 8; ++z) s[kk][z] += (float)x[z];
                }
            }
            if (craw > CAP) {                       // ~never taken
                unsigned no = *ovcnt; if (no > OVMAX) no = OVMAX;
                for (unsigned o = 0; o < no; ++o) {
                    if (ovlist[o * 2] == key) {
                        const bf16_t* src = fin + (size_t)ovlist[o * 2 + 1] * DDIM + kg * 8;
#pragma unroll
                        for (int kk = 0; kk < 4; ++kk) {
                            bf16x8 x = *reinterpret_cast<const bf16x8*>(src + kk * 32);
#pragma unroll
                            for (int z = 0; z < 8; ++z) s[kk][z] += (float)x[z];
                        }
                    }
                }
            }
#pragma unroll
            for (int kk = 0; kk < 4; ++kk)
#pragma unroll
                for (int z = 0; z < 8; ++z) af[kk][z] = (bf16_t)s[kk][z];
        }
        const bf16_t* wt = wcat_l + (size_t)t * 16384;
#pragma unroll
        for (int t8 = 0; t8 < 8; ++t8)
#pragma unroll
            for (int kk = 0; kk < 4; ++kk) {
                bf16x8 bfrag = *reinterpret_cast<const bf16x8*>(wt + (size_t)(t8 * 16 + li) * DDIM + kk * 32 + kg * 8);
                acc[t8] = __builtin_amdgcn_mfma_f32_16x16x32_bf16(af[kk], bfrag, acc[t8], 0, 0, 0);
            }
    }

    // reduce into LDS tile; C layout: row = kg*4+r, col = t8*16+li
#pragma unroll
    for (int t8 = 0; t8 < 8; ++t8)
#pragma unroll
        for (int r = 0; r < 4; ++r)
            atomicAdd(&tile[(kg * 4 + r) * 132 + t8 * 16 + li], acc[t8][r]);
    __syncthreads();

    // GN1 + ReLU: wave w handles rows w and w+8
#pragma unroll
    for (int rr = w; rr < 16; rr += 8) {
        float x0 = tile[rr * 132 + lane], x1 = tile[rr * 132 + 64 + lane];
        float s = x0 + x1, sq = x0 * x0 + x1 * x1;
#pragma unroll
        for (int off = 1; off < 64; off <<= 1) { s += __shfl_xor(s, off); sq += __shfl_xor(sq, off); }
        float mu = s * (1.f / 128.f);
        float var = sq * (1.f / 128.f) - mu * mu;
        float rstd = rsqrtf(var + 1e-5f);
        float y0 = fmaxf((x0 - mu) * rstd * g[lane] + b[lane], 0.f);
        float y1 = fmaxf((x1 - mu) * rstd * g[lane + 64] + b[lane + 64], 0.f);
        fout[(size_t)(row0 + rr) * DDIM + lane] = (bf16_t)y0;
        fout[(size_t)(row0 + rr) * DDIM + lane + 64] = (bf16_t)y1;
    }
}

// ---------------------------------------------------------------------------
// ctr2 GEMM + GN + residual + ReLU (in-place safe).
// ---------------------------------------------------------------------------
__global__ __launch_bounds__(256) void ctr2_gn_res(
    const bf16_t* __restrict__ x, const bf16_t* __restrict__ w,
    const float* __restrict__ g2, const float* __restrict__ b2,
    float* __restrict__ res, bf16_t* __restrict__ feat_bf_out, float* __restrict__ out_f32)
{
    const int lane = threadIdx.x & 63, wave = threadIdx.x >> 6;
    const int li = lane & 15, kg = lane >> 4;
    const int row0 = blockIdx.x * 64 + wave * 16;

    bf16x8 a[4];
#pragma unroll
    for (int kk = 0; kk < 4; ++kk)
        a[kk] = *reinterpret_cast<const bf16x8*>(x + (size_t)(row0 + li) * DDIM + kk * 32 + kg * 8);

    f32x4 acc[8];
#pragma unroll
    for (int t = 0; t < 8; ++t) {
        f32x4 c = {0.f, 0.f, 0.f, 0.f};
#pragma unroll
        for (int kk = 0; kk < 4; ++kk) {
            bf16x8 b = *reinterpret_cast<const bf16x8*>(w + (size_t)(t * 16 + li) * DDIM + kk * 32 + kg * 8);
            c = __builtin_amdgcn_mfma_f32_16x16x32_bf16(a[kk], b, c, 0, 0, 0);
        }
        acc[t] = c;
    }

    float mean[4], rstd[4];
#pragma unroll
    for (int r = 0; r < 4; ++r) {
        float s = 0.f, sq = 0.f;
#pragma unroll
        for (int t = 0; t < 8; ++t) { float v = acc[t][r]; s += v; sq += v * v; }
#pragma unroll
        for (int msk = 1; msk < 16; msk <<= 1) { s += __shfl_xor(s, msk); sq += __shfl_xor(sq, msk); }
        float mu = s * (1.f / 128.f);
        float var = sq * (1.f / 128.f) - mu * mu;
        mean[r] = mu;
        rstd[r] = rsqrtf(var + 1e-5f);
    }

#pragma unroll
    for (int t = 0; t < 8; ++t) {
        int c = t * 16 + li;
        float gg = g2[c], bb = b2[c];
#pragma unroll
        for (int r = 0; r < 4; ++r) {
            size_t idx = (size_t)(row0 + kg * 4 + r) * DDIM + c;
            float y = (acc[t][r] - mean[r]) * rstd[r] * gg + bb;
            float f = fmaxf(y + res[idx], 0.f);
            res[idx] = f;
            feat_bf_out[idx] = (bf16_t)f;
            if (out_f32) out_f32[idx] = f;
        }
    }
}

// ---------------------------------------------------------------------------
// Host launch
// ---------------------------------------------------------------------------
extern "C" void kernel_launch(void* const* d_in, const int* in_sizes, int n_in,
                              void* d_out, int out_size, void* d_ws, size_t ws_size,
                              hipStream_t stream) {
    const float* ctrs   = (const float*)d_in[0];
    const float* feats  = (const float*)d_in[1];
    const float* Wq     = (const float*)d_in[2];
    const float* Wk     = (const float*)d_in[3];
    const float* Wv     = (const float*)d_in[4];
    const float* W_ctr  = (const float*)d_in[5];
    const float* W_pre  = (const float*)d_in[6];
    const float* W_suc  = (const float*)d_in[7];
    const float* W_left = (const float*)d_in[8];
    const float* W_right= (const float*)d_in[9];
    const float* W_ctr2 = (const float*)d_in[10];
    const float* gn_g   = (const float*)d_in[11];
    const float* gn_b   = (const float*)d_in[12];
    const float* gn2_g  = (const float*)d_in[13];
    const float* gn2_b  = (const float*)d_in[14];
    const int* pre_u    = (const int*)d_in[15];
    const int* pre_v    = (const int*)d_in[16];
    const int* suc_u    = (const int*)d_in[17];
    const int* suc_v    = (const int*)d_in[18];
    const int* left_u   = (const int*)d_in[19];
    const int* left_v   = (const int*)d_in[20];
    const int* right_u  = (const int*)d_in[21];
    const int* right_v  = (const int*)d_in[22];
    (void)in_sizes; (void)n_in; (void)out_size; (void)ws_size;

    size_t off = 0;
    auto alloc = [&](size_t bytes) -> void* {
        void* p = (char*)d_ws + off;
        off += (bytes + 255) & ~(size_t)255;
        return p;
    };
    // persistent region
    bf16_t* wq_b    = (bf16_t*)alloc(16384 * 2);
    bf16_t* wk_b    = (bf16_t*)alloc(16384 * 2);
    bf16_t* wv_b    = (bf16_t*)alloc(16384 * 2);
    bf16_t* wctr2_b = (bf16_t*)alloc(65536 * 2);
    bf16_t* wcat    = (bf16_t*)alloc((size_t)4 * 15 * 16384 * 2);
    bf16_t* featA   = (bf16_t*)alloc((size_t)MROWS * DDIM * 2);
    bf16_t* featB   = (bf16_t*)alloc((size_t)MROWS * DDIM * 2);
    float*  res_f   = (float*)alloc((size_t)MROWS * DDIM * 4);
    unsigned* cnt   = (unsigned*)alloc((size_t)NKEY * 4);
    unsigned* ovcnt = (unsigned*)alloc(256);
    int*    csr     = (int*)alloc((size_t)NKEY * CAP * 4);
    int*    ovlist  = (int*)alloc((size_t)OVMAX * 2 * 4);

    // attention-phase temporaries (dead after attn_combine)
    bf16_t* ctrs_b  = (bf16_t*)alloc((size_t)MROWS * DDIM * 2);
    bf16_t* feats_b = (bf16_t*)alloc((size_t)MROWS * DDIM * 2);
    bf16_t* q_b     = (bf16_t*)alloc((size_t)MROWS * DDIM * 2);
    bf16_t* k_b     = (bf16_t*)alloc((size_t)MROWS * DDIM * 2);
    bf16_t* vT_b    = (bf16_t*)alloc((size_t)MROWS * DDIM * 2);
    float*  pm      = (float*)alloc((size_t)NCHUNK * MROWS * 4);
    float*  pl      = (float*)alloc((size_t)NCHUNK * MROWS * 4);
    float*  pO      = (float*)alloc((size_t)NCHUNK * MROWS * DDIM * 4);

    // --- preprocessing ---
    hipMemsetAsync(cnt, 0, (size_t)NKEY * 4 + 256, stream);  // cnt + ovcnt

    CvtArgs ca;
    ca.src[0] = ctrs;   ca.dst[0] = ctrs_b;  ca.n4[0] = MROWS * DDIM / 4;
    ca.src[1] = feats;  ca.dst[1] = feats_b; ca.n4[1] = MROWS * DDIM / 4;
    ca.src[2] = Wq;     ca.dst[2] = wq_b;    ca.n4[2] = 16384 / 4;
    ca.src[3] = Wk;     ca.dst[3] = wk_b;    ca.n4[3] = 16384 / 4;
    ca.src[4] = Wv;     ca.dst[4] = wv_b;    ca.n4[4] = 16384 / 4;
    ca.src[5] = W_ctr2; ca.dst[5] = wctr2_b; ca.n4[5] = 65536 / 4;
    int total4 = (2 * MROWS * DDIM + 3 * 16384 + 65536) / 4;
    cvt_multi<<<dim3((total4 + 255) / 256), dim3(256), 0, stream>>>(ca, total4);

    cvt_wcat<<<dim3((4 * 15 * 16384 / 4 + 255) / 256), dim3(256), 0, stream>>>(
        W_ctr, W_pre, W_suc, W_left, W_right, wcat);

    build_csr<<<dim3(NTYPE * EEDGE / 256), dim3(256), 0, stream>>>(
        pre_u, pre_v, suc_u, suc_v, left_u, left_v, right_u, right_v,
        cnt, csr, ovcnt, ovlist);

    // --- attention ---
    qkv_gemm<<<dim3(MROWS / 64, 3), dim3(256), 0, stream>>>(
        ctrs_b, feats_b, wq_b, wk_b, wv_b, q_b, k_b, vT_b);

    flash_attn<<<dim3(NSEQ / 64, NBATCH, NCHUNK), dim3(256), 0, stream>>>(
        q_b, k_b, vT_b, pO, pm, pl);

    attn_combine<<<dim3(MROWS * DDIM / 256), dim3(256), 0, stream>>>(
        pO, pm, pl, feats, featA, res_f);

    // --- fusion layers ---
    bf16_t* cur = featA;
    bf16_t* nxt = featB;
    for (int i = 0; i < 4; ++i) {
        layer_fused2<<<dim3(MROWS / 16), dim3(512), 0, stream>>>(
            cur, wcat + (size_t)i * 15 * 16384, cnt, csr, ovcnt, ovlist,
            gn_g + i * 128, gn_b + i * 128, nxt);
        ctr2_gn_res<<<dim3(MROWS / 64), dim3(256), 0, stream>>>(
            nxt, wctr2_b + (size_t)i * 16384, gn2_g + i * 128, gn2_b + i * 128,
            res_f, nxt, (i == 3) ? (float*)d_out : nullptr);
        bf16_t* tmp = cur; cur = nxt; nxt = tmp;
    }
}

// Round 6
// 681.799 us; speedup vs baseline: 1.3634x; 1.2241x over previous
//
#include <hip/hip_runtime.h>
#include <hip/hip_bf16.h>

// ---------------------------------------------------------------------------
// SparseLaneAttention on MI355X (gfx950) — round 6.
// r5 post-mortem: all "gather random rows into MFMA A-fragments" variants
// cluster at 100-145us/layer with every pipe idle — the per-lane divergent
// gather (16 random 256B rows per load instr) is the limiter. Fix by
// commutation: Y_t = feat@W_t densely (regular GEMM, proven shape), then the
// edge sum is a row-gather of Y (16 consecutive lanes read ONE row ->
// coalesced), fused with GN1+ReLU+ctr2+GN2+res+ReLU in one tail kernel.
// ---------------------------------------------------------------------------

typedef __bf16 bf16_t;
typedef __attribute__((ext_vector_type(8))) __bf16 bf16x8;
typedef __attribute__((ext_vector_type(4))) __bf16 bf16x4;
typedef __attribute__((ext_vector_type(4))) float f32x4;

#define MROWS 16384   // B*N
#define DDIM  128
#define EEDGE 32768
#define NSEQ  1024
#define NBATCH 16
#define CAP   16
#define NTYPE 14
#define NKEY  (NTYPE * MROWS)
#define OVMAX 4096
#define NCHUNK 4      // flash KV split

// ---------------------------------------------------------------------------
// Multi-segment f32 -> bf16 conversion
// ---------------------------------------------------------------------------
struct CvtArgs {
    const float* src[6];
    bf16_t* dst[6];
    int n4[6];
};

__global__ __launch_bounds__(256) void cvt_multi(CvtArgs a, int total4) {
    int i = blockIdx.x * 256 + threadIdx.x;
    if (i >= total4) return;
    int k = 0, base = 0;
    while (i - base >= a.n4[k]) { base += a.n4[k]; ++k; }
    int j = i - base;
    float4 v = reinterpret_cast<const float4*>(a.src[k])[j];
    bf16x4 o = { (bf16_t)v.x, (bf16_t)v.y, (bf16_t)v.z, (bf16_t)v.w };
    reinterpret_cast<bf16x4*>(a.dst[k])[j] = o;
}

// ---------------------------------------------------------------------------
// wcat[layer][15][128][128] bf16; slots 0..5 pre, 6..11 suc, 12 left,
// 13 right, 14 ctr.
// ---------------------------------------------------------------------------
__global__ __launch_bounds__(256) void cvt_wcat(
    const float* __restrict__ W_ctr, const float* __restrict__ W_pre,
    const float* __restrict__ W_suc, const float* __restrict__ W_left,
    const float* __restrict__ W_right, bf16_t* __restrict__ wcat)
{
    int tid = blockIdx.x * 256 + threadIdx.x;
    int idx = tid * 4;
    if (idx >= 4 * 15 * 16384) return;
    const int PER_I = 15 * 16384;
    int i = idx / PER_I, rem = idx % PER_I;
    int slot = rem / 16384, k = rem % 16384;
    const float* src;
    if (slot < 6)       src = W_pre  + ((size_t)(i * 6 + slot) * 16384 + k);
    else if (slot < 12) src = W_suc  + ((size_t)(i * 6 + slot - 6) * 16384 + k);
    else if (slot == 12) src = W_left  + ((size_t)i * 16384 + k);
    else if (slot == 13) src = W_right + ((size_t)i * 16384 + k);
    else                 src = W_ctr   + ((size_t)i * 16384 + k);
    float4 v = *reinterpret_cast<const float4*>(src);
    bf16x4 o = { (bf16_t)v.x, (bf16_t)v.y, (bf16_t)v.z, (bf16_t)v.w };
    *reinterpret_cast<bf16x4*>(wcat + idx) = o;
}

// ---------------------------------------------------------------------------
// Build CSR (once per call; indices are call-invariant).
// ---------------------------------------------------------------------------
__global__ __launch_bounds__(256) void build_csr(
    const int* __restrict__ pre_u, const int* __restrict__ pre_v,
    const int* __restrict__ suc_u, const int* __restrict__ suc_v,
    const int* __restrict__ left_u, const int* __restrict__ left_v,
    const int* __restrict__ right_u, const int* __restrict__ right_v,
    unsigned* __restrict__ cnt, int* __restrict__ csr,
    unsigned* __restrict__ ovcnt, int* __restrict__ ovlist)
{
    int tid = blockIdx.x * 256 + threadIdx.x;
    int t = tid >> 15, e = tid & (EEDGE - 1);
    const int* ua; const int* va;
    if (t < 6)        { ua = pre_u + t * EEDGE;       va = pre_v + t * EEDGE; }
    else if (t < 12)  { ua = suc_u + (t - 6) * EEDGE; va = suc_v + (t - 6) * EEDGE; }
    else if (t == 12) { ua = left_u;  va = left_v; }
    else              { ua = right_u; va = right_v; }
    int u = ua[e], v = va[e];
    int key = t * MROWS + u;
    unsigned slot = atomicAdd(&cnt[key], 1u);
    if (slot < CAP) csr[key * CAP + slot] = v;
    else {
        unsigned o = atomicAdd(ovcnt, 1u);
        if (o < OVMAX) { ovlist[o * 2] = key; ovlist[o * 2 + 1] = v; }
    }
}

// ---------------------------------------------------------------------------
// QKV projection.
// ---------------------------------------------------------------------------
__global__ __launch_bounds__(256) void qkv_gemm(
    const bf16_t* __restrict__ ctrs_bf, const bf16_t* __restrict__ feats_bf,
    const bf16_t* __restrict__ wq, const bf16_t* __restrict__ wk, const bf16_t* __restrict__ wv,
    bf16_t* __restrict__ q_out, bf16_t* __restrict__ k_out, bf16_t* __restrict__ vT_out)
{
    const int which = blockIdx.y;
    const bf16_t* x = (which == 0) ? ctrs_bf : feats_bf;
    const bf16_t* w = (which == 0) ? wq : (which == 1) ? wk : wv;
    const int lane = threadIdx.x & 63, wave = threadIdx.x >> 6;
    const int li = lane & 15, kg = lane >> 4;
    const int row0 = blockIdx.x * 64 + wave * 16;

    bf16x8 a[4];
#pragma unroll
    for (int kk = 0; kk < 4; ++kk)
        a[kk] = *reinterpret_cast<const bf16x8*>(x + (size_t)(row0 + li) * DDIM + kk * 32 + kg * 8);

    f32x4 acc[8];
#pragma unroll
    for (int t = 0; t < 8; ++t) {
        f32x4 c = {0.f, 0.f, 0.f, 0.f};
#pragma unroll
        for (int kk = 0; kk < 4; ++kk) {
            bf16x8 b = *reinterpret_cast<const bf16x8*>(w + (size_t)(t * 16 + li) * DDIM + kk * 32 + kg * 8);
            c = __builtin_amdgcn_mfma_f32_16x16x32_bf16(a[kk], b, c, 0, 0, 0);
        }
        acc[t] = c;
    }

    if (which < 2) {
        bf16_t* out = (which == 0) ? q_out : k_out;
#pragma unroll
        for (int t = 0; t < 8; ++t) {
            int c = t * 16 + li;
#pragma unroll
            for (int r = 0; r < 4; ++r)
                out[(size_t)(row0 + kg * 4 + r) * DDIM + c] = (bf16_t)acc[t][r];
        }
    } else {
        const int bb = row0 >> 10;
        const int jb = (row0 & 1023) + kg * 4;
#pragma unroll
        for (int t = 0; t < 8; ++t) {
            int c = t * 16 + li;
            bf16x4 pk = { (bf16_t)acc[t][0], (bf16_t)acc[t][1], (bf16_t)acc[t][2], (bf16_t)acc[t][3] };
            *reinterpret_cast<bf16x4*>(vT_out + ((size_t)bb * 128 + c) * NSEQ + jb) = pk;
        }
    }
}

// ---------------------------------------------------------------------------
// Flash attention, KV-split (unchanged from r5).
// ---------------------------------------------------------------------------
__global__ __launch_bounds__(256) void flash_attn(
    const bf16_t* __restrict__ q, const bf16_t* __restrict__ k,
    const bf16_t* __restrict__ vT,
    float* __restrict__ pO, float* __restrict__ pm, float* __restrict__ pl)
{
    const int lane = threadIdx.x & 63, wave = threadIdx.x >> 6;
    const int li = lane & 15, kg = lane >> 4;
    const int b = blockIdx.y;
    const int chunk = blockIdx.z;
    const int i0 = blockIdx.x * 64 + wave * 16;

    __shared__ bf16_t p_lds[4][16][48];

    bf16x8 qf[4];
#pragma unroll
    for (int kk = 0; kk < 4; ++kk)
        qf[kk] = *reinterpret_cast<const bf16x8*>(q + ((size_t)b * NSEQ + i0 + li) * DDIM + kk * 32 + kg * 8);

    float m_run = -1e30f, l_run = 0.f;
    f32x4 o[8];
#pragma unroll
    for (int t = 0; t < 8; ++t) o[t] = f32x4{0.f, 0.f, 0.f, 0.f};

    const float nf = 0.08838834764831845f;
    const int jlo = chunk * (NSEQ / NCHUNK), jhi = jlo + NSEQ / NCHUNK;

    for (int j0 = jlo; j0 < jhi; j0 += 32) {
        f32x4 s[2];
#pragma unroll
        for (int sub = 0; sub < 2; ++sub) {
            f32x4 c = {0.f, 0.f, 0.f, 0.f};
#pragma unroll
            for (int kk = 0; kk < 4; ++kk) {
                bf16x8 a = *reinterpret_cast<const bf16x8*>(
                    k + ((size_t)b * NSEQ + j0 + sub * 16 + li) * DDIM + kk * 32 + kg * 8);
                c = __builtin_amdgcn_mfma_f32_16x16x32_bf16(a, qf[kk], c, 0, 0, 0);
            }
            s[sub] = c;
        }
        float smax = -1e30f;
#pragma unroll
        for (int sub = 0; sub < 2; ++sub)
#pragma unroll
            for (int r = 0; r < 4; ++r) { s[sub][r] *= nf; smax = fmaxf(smax, s[sub][r]); }
        smax = fmaxf(smax, __shfl_xor(smax, 16));
        smax = fmaxf(smax, __shfl_xor(smax, 32));
        float m_new = fmaxf(m_run, smax);
        float alpha = __expf(m_run - m_new);
        float psum = 0.f;
#pragma unroll
        for (int sub = 0; sub < 2; ++sub) {
            bf16x4 pk;
#pragma unroll
            for (int r = 0; r < 4; ++r) {
                float p = __expf(s[sub][r] - m_new);
                psum += p;
                pk[r] = (bf16_t)p;
            }
            *reinterpret_cast<bf16x4*>(&p_lds[wave][li][sub * 16 + kg * 4]) = pk;
        }
        psum += __shfl_xor(psum, 16);
        psum += __shfl_xor(psum, 32);
        l_run = l_run * alpha + psum;
        m_run = m_new;

        float al[4];
#pragma unroll
        for (int r = 0; r < 4; ++r) al[r] = __shfl(alpha, kg * 4 + r);

        asm volatile("s_waitcnt lgkmcnt(0)" ::: "memory");
        __builtin_amdgcn_sched_barrier(0);

        bf16x8 pa = *reinterpret_cast<const bf16x8*>(&p_lds[wave][li][kg * 8]);

#pragma unroll
        for (int t = 0; t < 8; ++t)
#pragma unroll
            for (int r = 0; r < 4; ++r) o[t][r] *= al[r];

#pragma unroll
        for (int t = 0; t < 8; ++t) {
            bf16x8 vb = *reinterpret_cast<const bf16x8*>(
                vT + ((size_t)b * 128 + t * 16 + li) * NSEQ + j0 + kg * 8);
            o[t] = __builtin_amdgcn_mfma_f32_16x16x32_bf16(pa, vb, o[t], 0, 0, 0);
        }
    }

#pragma unroll
    for (int t = 0; t < 8; ++t) {
        int c = t * 16 + li;
#pragma unroll
        for (int r = 0; r < 4; ++r) {
            size_t m = (size_t)b * NSEQ + i0 + kg * 4 + r;
            pO[((size_t)chunk * MROWS + m) * DDIM + c] = o[t][r];
        }
    }
    float m_r[4], l_r[4];
#pragma unroll
    for (int r = 0; r < 4; ++r) { m_r[r] = __shfl(m_run, kg * 4 + r); l_r[r] = __shfl(l_run, kg * 4 + r); }
    if (li == 0) {
#pragma unroll
        for (int r = 0; r < 4; ++r) {
            size_t m = (size_t)b * NSEQ + i0 + kg * 4 + r;
            pm[(size_t)chunk * MROWS + m] = m_r[r];
            pl[(size_t)chunk * MROWS + m] = l_r[r];
        }
    }
}

// ---------------------------------------------------------------------------
// Combine chunk partials (exact) -> feat = feats + att.
// ---------------------------------------------------------------------------
__global__ __launch_bounds__(256) void attn_combine(
    const float* __restrict__ pO, const float* __restrict__ pm, const float* __restrict__ pl,
    const float* __restrict__ feats, bf16_t* __restrict__ feat_bf, float* __restrict__ res)
{
    int idx = blockIdx.x * 256 + threadIdx.x;
    int row = idx >> 7;
    float mx = -1e30f;
#pragma unroll
    for (int c = 0; c < NCHUNK; ++c) mx = fmaxf(mx, pm[(size_t)c * MROWS + row]);
    float num = 0.f, den = 0.f;
#pragma unroll
    for (int c = 0; c < NCHUNK; ++c) {
        float wgt = __expf(pm[(size_t)c * MROWS + row] - mx);
        den += wgt * pl[(size_t)c * MROWS + row];
        num += wgt * pO[((size_t)c * MROWS + row) * DDIM + (idx & 127)];
    }
    float f = feats[idx] + num / den;
    feat_bf[idx] = (bf16_t)f;
    res[idx] = f;
}

// ---------------------------------------------------------------------------
// Y_t = fin @ W_t^T for all 15 slots (14 edge types + ctr), bf16 out.
// Dense, regular, high-occupancy: grid (M/64, 15).
// ---------------------------------------------------------------------------
__global__ __launch_bounds__(256) void ymat(
    const bf16_t* __restrict__ fin, const bf16_t* __restrict__ wcat_l,
    bf16_t* __restrict__ Y)
{
    const int t = blockIdx.y;
    const bf16_t* w = wcat_l + (size_t)t * 16384;
    bf16_t* out = Y + (size_t)t * MROWS * DDIM;
    const int lane = threadIdx.x & 63, wave = threadIdx.x >> 6;
    const int li = lane & 15, kg = lane >> 4;
    const int row0 = blockIdx.x * 64 + wave * 16;

    bf16x8 a[4];
#pragma unroll
    for (int kk = 0; kk < 4; ++kk)
        a[kk] = *reinterpret_cast<const bf16x8*>(fin + (size_t)(row0 + li) * DDIM + kk * 32 + kg * 8);

#pragma unroll
    for (int t8 = 0; t8 < 8; ++t8) {
        f32x4 c = {0.f, 0.f, 0.f, 0.f};
#pragma unroll
        for (int kk = 0; kk < 4; ++kk) {
            bf16x8 b = *reinterpret_cast<const bf16x8*>(w + (size_t)(t8 * 16 + li) * DDIM + kk * 32 + kg * 8);
            c = __builtin_amdgcn_mfma_f32_16x16x32_bf16(a[kk], b, c, 0, 0, 0);
        }
        int col = t8 * 16 + li;
#pragma unroll
        for (int r = 0; r < 4; ++r)
            out[(size_t)(row0 + kg * 4 + r) * DDIM + col] = (bf16_t)c[r];
    }
}

// ---------------------------------------------------------------------------
// Gather + full layer tail.  Block = 16 dest rows, 256 threads.
// Thread (r = tid>>4, lp = tid&15) owns 8 channels of row r: the 16 lanes of
// a row-group read CONSECUTIVE 16B chunks of each gathered Y row (coalesced),
// and the CSR c-loop is uniform within the group (no lane divergence).
// temp = Y14[row] + sum_t sum_j Yt[csr[t,row,j]]  (all in f32 regs)
// -> GN1+ReLU -> LDS -> ctr2 MFMA GEMM -> GN2 + res + ReLU -> fout/res/d_out.
// ---------------------------------------------------------------------------
__global__ __launch_bounds__(256) void gather_tail(
    const bf16_t* __restrict__ Y,
    const unsigned* __restrict__ cnt, const int* __restrict__ csr,
    const unsigned* __restrict__ ovcnt, const int* __restrict__ ovlist,
    const bf16_t* __restrict__ wctr2_l,
    const float* __restrict__ g1, const float* __restrict__ b1,
    const float* __restrict__ g2, const float* __restrict__ b2,
    float* __restrict__ res, bf16_t* __restrict__ fout, float* __restrict__ out_f32)
{
    __shared__ bf16_t yA[16][136];   // 272B row stride -> banks spread by 4
    __shared__ float  t2[16][132];   // 528B row stride -> banks spread by 4
    const int tid = threadIdx.x;
    const int r = tid >> 4, lp = tid & 15;
    const int row0 = blockIdx.x * 16;
    const int row = row0 + r;
    const int ch = lp * 8;

    float s[8];
    // ctr slab (slot 14), unconditional
    {
        bf16x8 x = *reinterpret_cast<const bf16x8*>(Y + ((size_t)14 * MROWS + row) * DDIM + ch);
#pragma unroll
        for (int z = 0; z < 8; ++z) s[z] = (float)x[z];
    }

    for (int t = 0; t < NTYPE; ++t) {
        const int key = t * MROWS + row;
        const unsigned craw = cnt[key];
        const int c = (int)(craw < CAP ? craw : CAP);
        const int4* lst4 = reinterpret_cast<const int4*>(csr + (size_t)key * CAP);
        const bf16_t* Yt = Y + (size_t)t * MROWS * DDIM;
#pragma unroll
        for (int q = 0; q < 4; ++q) {
            if (q * 4 < c) {
                int4 quad = lst4[q];
                if (q * 4 + 0 < c) {
                    bf16x8 x = *reinterpret_cast<const bf16x8*>(Yt + (size_t)quad.x * DDIM + ch);
#pragma unroll
                    for (int z = 0; z < 8; ++z) s[z] += (float)x[z];
                }
                if (q * 4 + 1 < c) {
                    bf16x8 x = *reinterpret_cast<const bf16x8*>(Yt + (size_t)quad.y * DDIM + ch);
#pragma unroll
                    for (int z = 0; z < 8; ++z) s[z] += (float)x[z];
                }
                if (q * 4 + 2 < c) {
                    bf16x8 x = *reinterpret_cast<const bf16x8*>(Yt + (size_t)quad.z * DDIM + ch);
#pragma unroll
                    for (int z = 0; z < 8; ++z) s[z] += (float)x[z];
                }
                if (q * 4 + 3 < c) {
                    bf16x8 x = *reinterpret_cast<const bf16x8*>(Yt + (size_t)quad.w * DDIM + ch);
#pragma unroll
                    for (int z = 0; z < 8; ++z) s[z] += (float)x[z];
                }
            }
        }
        if (craw > CAP) {                       // ~never taken
            unsigned no = *ovcnt; if (no > OVMAX) no = OVMAX;
            for (unsigned o = 0; o < no; ++o) {
                if (ovlist[o * 2] == key) {
                    bf16x8 x = *reinterpret_cast<const bf16x8*>(Yt + (size_t)ovlist[o * 2 + 1] * DDIM + ch);
#pragma unroll
                    for (int z = 0; z < 8; ++z) s[z] += (float)x[z];
                }
            }
        }
    }

    // ---- GN1 + ReLU (stats over the 16-lane row-group) ----
    {
        float sm = 0.f, sq = 0.f;
#pragma unroll
        for (int z = 0; z < 8; ++z) { sm += s[z]; sq += s[z] * s[z]; }
#pragma unroll
        for (int off = 1; off < 16; off <<= 1) { sm += __shfl_xor(sm, off); sq += __shfl_xor(sq, off); }
        float mu = sm * (1.f / 128.f);
        float var = sq * (1.f / 128.f) - mu * mu;
        float rstd = rsqrtf(var + 1e-5f);
        bf16x8 yv;
#pragma unroll
        for (int z = 0; z < 8; ++z) {
            float y = fmaxf((s[z] - mu) * rstd * g1[ch + z] + b1[ch + z], 0.f);
            yv[z] = (bf16_t)y;
        }
        *reinterpret_cast<bf16x8*>(&yA[r][ch]) = yv;
    }
    __syncthreads();

    // ---- ctr2 GEMM from LDS (wave w covers cols w*32..w*32+31) ----
    {
        const int lane = tid & 63, w = tid >> 6;
        const int li = lane & 15, kg = lane >> 4;
        bf16x8 a2[4];
#pragma unroll
        for (int kk = 0; kk < 4; ++kk)
            a2[kk] = *reinterpret_cast<const bf16x8*>(&yA[li][kk * 32 + kg * 8]);
#pragma unroll
        for (int u = 0; u < 2; ++u) {
            const int t8 = w * 2 + u;
            f32x4 c = {0.f, 0.f, 0.f, 0.f};
#pragma unroll
            for (int kk = 0; kk < 4; ++kk) {
                bf16x8 b = *reinterpret_cast<const bf16x8*>(wctr2_l + (size_t)(t8 * 16 + li) * DDIM + kk * 32 + kg * 8);
                c = __builtin_amdgcn_mfma_f32_16x16x32_bf16(a2[kk], b, c, 0, 0, 0);
            }
#pragma unroll
            for (int rr = 0; rr < 4; ++rr)
                t2[kg * 4 + rr][t8 * 16 + li] = c[rr];
        }
    }
    __syncthreads();

    // ---- GN2 + residual + ReLU (back to (r,lp) mapping) ----
    {
        float v[8];
#pragma unroll
        for (int z = 0; z < 8; ++z) v[z] = t2[r][ch + z];
        float sm = 0.f, sq = 0.f;
#pragma unroll
        for (int z = 0; z < 8; ++z) { sm += v[z]; sq += v[z] * v[z]; }
#pragma unroll
        for (int off = 1; off < 16; off <<= 1) { sm += __shfl_xor(sm, off); sq += __shfl_xor(sq, off); }
        float mu = sm * (1.f / 128.f);
        float var = sq * (1.f / 128.f) - mu * mu;
        float rstd = rsqrtf(var + 1e-5f);

        size_t base = (size_t)row * DDIM + ch;
        float rv[8];
        *reinterpret_cast<float4*>(&rv[0]) = *reinterpret_cast<const float4*>(res + base);
        *reinterpret_cast<float4*>(&rv[4]) = *reinterpret_cast<const float4*>(res + base + 4);
        bf16x8 fo;
#pragma unroll
        for (int z = 0; z < 8; ++z) {
            float y = (v[z] - mu) * rstd * g2[ch + z] + b2[ch + z];
            float f = fmaxf(y + rv[z], 0.f);
            rv[z] = f;
            fo[z] = (bf16_t)f;
        }
        *reinterpret_cast<float4*>(res + base) = *reinterpret_cast<float4*>(&rv[0]);
        *reinterpret_cast<float4*>(res + base + 4) = *reinterpret_cast<float4*>(&rv[4]);
        *reinterpret_cast<bf16x8*>(fout + base) = fo;
        if (out_f32) {
            *reinterpret_cast<float4*>(out_f32 + base) = *reinterpret_cast<float4*>(&rv[0]);
            *reinterpret_cast<float4*>(out_f32 + base + 4) = *reinterpret_cast<float4*>(&rv[4]);
        }
    }
}

// ---------------------------------------------------------------------------
// Host launch
// ---------------------------------------------------------------------------
extern "C" void kernel_launch(void* const* d_in, const int* in_sizes, int n_in,
                              void* d_out, int out_size, void* d_ws, size_t ws_size,
                              hipStream_t stream) {
    const float* ctrs   = (const float*)d_in[0];
    const float* feats  = (const float*)d_in[1];
    const float* Wq     = (const float*)d_in[2];
    const float* Wk     = (const float*)d_in[3];
    const float* Wv     = (const float*)d_in[4];
    const float* W_ctr  = (const float*)d_in[5];
    const float* W_pre  = (const float*)d_in[6];
    const float* W_suc  = (const float*)d_in[7];
    const float* W_left = (const float*)d_in[8];
    const float* W_right= (const float*)d_in[9];
    const float* W_ctr2 = (const float*)d_in[10];
    const float* gn_g   = (const float*)d_in[11];
    const float* gn_b   = (const float*)d_in[12];
    const float* gn2_g  = (const float*)d_in[13];
    const float* gn2_b  = (const float*)d_in[14];
    const int* pre_u    = (const int*)d_in[15];
    const int* pre_v    = (const int*)d_in[16];
    const int* suc_u    = (const int*)d_in[17];
    const int* suc_v    = (const int*)d_in[18];
    const int* left_u   = (const int*)d_in[19];
    const int* left_v   = (const int*)d_in[20];
    const int* right_u  = (const int*)d_in[21];
    const int* right_v  = (const int*)d_in[22];
    (void)in_sizes; (void)n_in; (void)out_size; (void)ws_size;

    size_t off = 0;
    auto alloc = [&](size_t bytes) -> void* {
        void* p = (char*)d_ws + off;
        off += (bytes + 255) & ~(size_t)255;
        return p;
    };
    // persistent region
    bf16_t* wq_b    = (bf16_t*)alloc(16384 * 2);
    bf16_t* wk_b    = (bf16_t*)alloc(16384 * 2);
    bf16_t* wv_b    = (bf16_t*)alloc(16384 * 2);
    bf16_t* wctr2_b = (bf16_t*)alloc(65536 * 2);
    bf16_t* wcat    = (bf16_t*)alloc((size_t)4 * 15 * 16384 * 2);
    bf16_t* featA   = (bf16_t*)alloc((size_t)MROWS * DDIM * 2);
    bf16_t* featB   = (bf16_t*)alloc((size_t)MROWS * DDIM * 2);
    float*  res_f   = (float*)alloc((size_t)MROWS * DDIM * 4);
    unsigned* cnt   = (unsigned*)alloc((size_t)NKEY * 4);
    unsigned* ovcnt = (unsigned*)alloc(256);
    int*    csr     = (int*)alloc((size_t)NKEY * CAP * 4);
    int*    ovlist  = (int*)alloc((size_t)OVMAX * 2 * 4);

    // union region: attention-phase temporaries vs per-layer Y slabs
    size_t ubase = off;
    bf16_t* ctrs_b  = (bf16_t*)alloc((size_t)MROWS * DDIM * 2);
    bf16_t* feats_b = (bf16_t*)alloc((size_t)MROWS * DDIM * 2);
    bf16_t* q_b     = (bf16_t*)alloc((size_t)MROWS * DDIM * 2);
    bf16_t* k_b     = (bf16_t*)alloc((size_t)MROWS * DDIM * 2);
    bf16_t* vT_b    = (bf16_t*)alloc((size_t)MROWS * DDIM * 2);
    float*  pm      = (float*)alloc((size_t)NCHUNK * MROWS * 4);
    float*  pl      = (float*)alloc((size_t)NCHUNK * MROWS * 4);
    float*  pO      = (float*)alloc((size_t)NCHUNK * MROWS * DDIM * 4);
    bf16_t* Y       = (bf16_t*)((char*)d_ws + ubase);   // 15*M*128*2 = 62.9MB, aliases attn temps

    // --- preprocessing ---
    hipMemsetAsync(cnt, 0, (size_t)NKEY * 4 + 256, stream);  // cnt + ovcnt

    CvtArgs ca;
    ca.src[0] = ctrs;   ca.dst[0] = ctrs_b;  ca.n4[0] = MROWS * DDIM / 4;
    ca.src[1] = feats;  ca.dst[1] = feats_b; ca.n4[1] = MROWS * DDIM / 4;
    ca.src[2] = Wq;     ca.dst[2] = wq_b;    ca.n4[2] = 16384 / 4;
    ca.src[3] = Wk;     ca.dst[3] = wk_b;    ca.n4[3] = 16384 / 4;
    ca.src[4] = Wv;     ca.dst[4] = wv_b;    ca.n4[4] = 16384 / 4;
    ca.src[5] = W_ctr2; ca.dst[5] = wctr2_b; ca.n4[5] = 65536 / 4;
    int total4 = (2 * MROWS * DDIM + 3 * 16384 + 65536) / 4;
    cvt_multi<<<dim3((total4 + 255) / 256), dim3(256), 0, stream>>>(ca, total4);

    cvt_wcat<<<dim3((4 * 15 * 16384 / 4 + 255) / 256), dim3(256), 0, stream>>>(
        W_ctr, W_pre, W_suc, W_left, W_right, wcat);

    build_csr<<<dim3(NTYPE * EEDGE / 256), dim3(256), 0, stream>>>(
        pre_u, pre_v, suc_u, suc_v, left_u, left_v, right_u, right_v,
        cnt, csr, ovcnt, ovlist);

    // --- attention ---
    qkv_gemm<<<dim3(MROWS / 64, 3), dim3(256), 0, stream>>>(
        ctrs_b, feats_b, wq_b, wk_b, wv_b, q_b, k_b, vT_b);

    flash_attn<<<dim3(NSEQ / 64, NBATCH, NCHUNK), dim3(256), 0, stream>>>(
        q_b, k_b, vT_b, pO, pm, pl);

    attn_combine<<<dim3(MROWS * DDIM / 256), dim3(256), 0, stream>>>(
        pO, pm, pl, feats, featA, res_f);

    // --- fusion layers (attn temporaries now dead; Y reuses their space) ---
    bf16_t* cur = featA;
    bf16_t* nxt = featB;
    for (int i = 0; i < 4; ++i) {
        ymat<<<dim3(MROWS / 64, 15), dim3(256), 0, stream>>>(
            cur, wcat + (size_t)i * 15 * 16384, Y);
        gather_tail<<<dim3(MROWS / 16), dim3(256), 0, stream>>>(
            Y, cnt, csr, ovcnt, ovlist, wctr2_b + (size_t)i * 16384,
            gn_g + i * 128, gn_b + i * 128, gn2_g + i * 128, gn2_b + i * 128,
            res_f, nxt, (i == 3) ? (float*)d_out : nullptr);
        bf16_t* tmp = cur; cur = nxt; nxt = tmp;
    }
}